// Round 4
// baseline (469.194 us; speedup 1.0000x reference)
//
#include <hip/hip_runtime.h>
#include <hip/hip_bf16.h>

#define N_NODES 8192
#define IN_F 512
#define OUT_F 128
#define NSTRIPE 8                 // k-stripes per block = waves per block
#define KT_PER 32                 // 32-col k-tiles per stripe
#define NWORDS (N_NODES / 32)     // packed words per adj row = 256
#define LOG2E 1.4426950408889634f

typedef unsigned short u16;
typedef unsigned int u32;
typedef short s16x8 __attribute__((ext_vector_type(8)));
typedef float f32x4 __attribute__((ext_vector_type(4)));
typedef u32 u32x4 __attribute__((ext_vector_type(4)));

__device__ __forceinline__ u16 f2bf(float f) {
    union { float f; unsigned u; } x; x.f = f;
    unsigned r = x.u + 0x7FFFu + ((x.u >> 16) & 1u);
    return (u16)(r >> 16);
}

// HW pack: v_cvt_pk_bf16_f32 (rne) -> u32 (lo=a, hi=b)
__device__ __forceinline__ u32 packbf2(float a, float b) {
    __hip_bfloat162 h = __float22bfloat162_rn(make_float2(a, b));
    u32 u; __builtin_memcpy(&u, &h, 4);
    return u;
}

// edge weight: exp(sigmoid(alpha)) or 0 if masked
__device__ __forceinline__ float edge_p(float wh1, float w2, int keep) {
    float alpha = wh1 + w2;
    float e = exp2f(-LOG2E * alpha);
    float s = __builtin_amdgcn_rcpf(1.0f + e);
    float p = exp2f(LOG2E * s);
    return keep ? p : 0.0f;
}

// ---- K0: repack W [512x128] fp32 -> bf16 MFMA B-fragment layout
__global__ void repack_W(const float* __restrict__ W, u16* __restrict__ W_frag) {
    int tid = blockIdx.x * 256 + threadIdx.x;   // 0..65535
    int j = tid & 7;
    int lane = (tid >> 3) & 63;
    int nt = (tid >> 9) & 7;
    int kt = tid >> 12;
    int k = kt * 32 + (lane >> 4) * 8 + j;
    int n = nt * 16 + (lane & 15);
    W_frag[tid] = f2bf(W[k * OUT_F + n]);
}

// ---- Wa1 = W@a1, Wa2 = W@a2 (fp32, 512 each)
__global__ void compute_Wa(const float* __restrict__ W, const float* __restrict__ a1,
                           const float* __restrict__ a2,
                           float* __restrict__ Wa1, float* __restrict__ Wa2) {
    int k = blockIdx.x * 256 + threadIdx.x;
    if (k >= IN_F) return;
    float s1 = 0.f, s2 = 0.f;
    #pragma unroll 8
    for (int n = 0; n < OUT_F; n++) {
        float w = W[k * OUT_F + n];
        s1 += w * a1[n];
        s2 += w * a2[n];
    }
    Wa1[k] = s1; Wa2[k] = s2;
}

// ---- K-pack: adj int32 [8192x8192] -> 1-bit bitmap, 256 MB -> 8 MB.
// Pure streaming kernel: 2M threads, each consumes 32 contiguous ints
// (8 x int4; L1 absorbs the intra-wave 128B-stride re-touches) and emits
// one u32.  Bit b of word w  <->  col w*32 + b.
__global__ __launch_bounds__(256)
void pack_adj(const int* __restrict__ adj, u32* __restrict__ Pk) {
    int gid = blockIdx.x * 256 + threadIdx.x;       // word index, 2M total
    const int* src = adj + (size_t)gid * 32;
    u32 b = 0;
    #pragma unroll
    for (int t = 0; t < 8; t++) {
        int4 v = *(const int4*)(src + t * 4);
        b |= (u32)(v.x > 0) << (t * 4 + 0);
        b |= (u32)(v.y > 0) << (t * 4 + 1);
        b |= (u32)(v.z > 0) << (t * 4 + 2);
        b |= (u32)(v.w > 0) << (t * 4 + 3);
    }
    Pk[gid] = b;
}

// ---- K1: h = X@W (bf16 MFMA), scatter h to B-frag layout; Wh = X@Wa (fp32).
__global__ __launch_bounds__(256)
void gemm_h(const float* __restrict__ X, const u16* __restrict__ W_frag,
            const float* __restrict__ Wa1, const float* __restrict__ Wa2,
            float* __restrict__ Wh1, float* __restrict__ Wh2,
            u16* __restrict__ h_frag) {
    int tid = threadIdx.x;
    int wave = tid >> 6;
    int lane = tid & 63;
    int quad = lane >> 4;
    int lid = lane & 15;
    int rbase = blockIdx.x * 16;
    const float* xrow = X + (size_t)(rbase + lid) * IN_F;
    const s16x8* Wf = (const s16x8*)W_frag;
    f32x4 acc0 = {}, acc1 = {};
    float p1 = 0.f, p2 = 0.f;
    int nt0 = wave * 2;

    for (int kt = 0; kt < 16; kt++) {
        int k0 = kt * 32 + quad * 8;
        float4 x0 = *(const float4*)(xrow + k0);
        float4 x1 = *(const float4*)(xrow + k0 + 4);
        u32x4 uv;
        uv.x = packbf2(x0.x, x0.y); uv.y = packbf2(x0.z, x0.w);
        uv.z = packbf2(x1.x, x1.y); uv.w = packbf2(x1.z, x1.w);
        s16x8 a = __builtin_bit_cast(s16x8, uv);
        if (wave == 0) {
            float4 wa = *(const float4*)(Wa1 + k0);
            float4 wb = *(const float4*)(Wa1 + k0 + 4);
            float4 wc = *(const float4*)(Wa2 + k0);
            float4 wd = *(const float4*)(Wa2 + k0 + 4);
            p1 += x0.x*wa.x + x0.y*wa.y + x0.z*wa.z + x0.w*wa.w
                + x1.x*wb.x + x1.y*wb.y + x1.z*wb.z + x1.w*wb.w;
            p2 += x0.x*wc.x + x0.y*wc.y + x0.z*wc.z + x0.w*wc.w
                + x1.x*wd.x + x1.y*wd.y + x1.z*wd.z + x1.w*wd.w;
        }
        s16x8 b0 = Wf[(kt * 8 + nt0) * 64 + lane];
        s16x8 b1 = Wf[(kt * 8 + nt0 + 1) * 64 + lane];
        acc0 = __builtin_amdgcn_mfma_f32_16x16x32_bf16(a, b0, acc0, 0, 0, 0);
        acc1 = __builtin_amdgcn_mfma_f32_16x16x32_bf16(a, b1, acc1, 0, 0, 0);
    }

    #pragma unroll
    for (int reg = 0; reg < 4; reg++) {
        int row = rbase + quad * 4 + reg;
        int ktile = row >> 5, kl = row & 31;
        int lane2 = (kl >> 3) * 16 + lid, j2 = kl & 7;
        h_frag[(size_t)((ktile * 8 + nt0) * 64 + lane2) * 8 + j2] = f2bf(acc0[reg]);
        h_frag[(size_t)((ktile * 8 + nt0 + 1) * 64 + lane2) * 8 + j2] = f2bf(acc1[reg]);
    }
    if (wave == 0) {
        p1 += __shfl_xor(p1, 16, 64); p1 += __shfl_xor(p1, 32, 64);
        p2 += __shfl_xor(p2, 16, 64); p2 += __shfl_xor(p2, 32, 64);
        if (lane < 16) { Wh1[rbase + lid] = p1; Wh2[rbase + lid] = p2; }
    }
}

// ---- K2: fused attention on the PACKED adjacency. 256 blocks x 512 thr.
// Block owns 32 rows; wave p sweeps k-stripe [p*1024, p*1024+1024) over all
// 32 rows (acc0 = rows 0-15, acc1 = rows 16-31; B-fragment shared by both
// MFMAs). adj traffic: 1 u32/row/tile (Pk is 8 MB, L2/L3-resident); Wh2 and
// h_frag L1/L2-resident. Barrier-free sweep, depth-1 prefetch of the packed
// words per 4-tile group; LDS park + 16-slice finalize at the end.
__global__ __launch_bounds__(512)
void attn_fused(const u32* __restrict__ Pk, const float* __restrict__ Wh1,
                const float* __restrict__ Wh2, const u16* __restrict__ h_frag,
                float* __restrict__ out) {
    __shared__ f32x4 red[NSTRIPE][16][64];   // 128 KB acc park
    __shared__ float rsum_lds[NSTRIPE][32];  // 1 KB rowsums

    int tid = threadIdx.x;
    int wave = tid >> 6;         // = stripe p
    int lane = tid & 63;
    int quad = lane >> 4;
    int lid = lane & 15;
    int rbase = blockIdx.x * 32;
    int r0 = rbase + lid, r1 = r0 + 16;

    float wh10 = Wh1[r0], wh11 = Wh1[r1];
    f32x4 acc0[8] = {}, acc1[8] = {};
    float ps0 = 0.f, ps1 = 0.f;
    const s16x8* Hf = (const s16x8*)h_frag;
    const u32* prow0 = Pk + (size_t)r0 * NWORDS;
    const u32* prow1 = Pk + (size_t)r1 * NWORDS;

    const int kt0 = wave * KT_PER;

    // prologue: prefetch group 0's packed words (4 tiles per group)
    u32x4 P0 = *(const u32x4*)(prow0 + kt0);
    u32x4 P1 = *(const u32x4*)(prow1 + kt0);

    #pragma unroll 1
    for (int g = 0; g < KT_PER / 4; g++) {
        u32x4 c0 = P0, c1 = P1;
        int gn = (g + 1 < KT_PER / 4) ? g + 1 : g;   // clamp (no OOB)
        P0 = *(const u32x4*)(prow0 + kt0 + gn * 4);
        P1 = *(const u32x4*)(prow1 + kt0 + gn * 4);

        #pragma unroll
        for (int t = 0; t < 4; t++) {
            int kt = kt0 + g * 4 + t;
            int k0 = kt * 32 + quad * 8;
            u32 w0 = c0[t] >> (quad * 8);
            u32 w1 = c1[t] >> (quad * 8);
            float4 w20 = *(const float4*)(Wh2 + k0);
            float4 w21 = *(const float4*)(Wh2 + k0 + 4);

            float e0 = edge_p(wh10, w20.x, (w0 >> 0) & 1);
            float e1 = edge_p(wh10, w20.y, (w0 >> 1) & 1);
            float e2 = edge_p(wh10, w20.z, (w0 >> 2) & 1);
            float e3 = edge_p(wh10, w20.w, (w0 >> 3) & 1);
            float e4 = edge_p(wh10, w21.x, (w0 >> 4) & 1);
            float e5 = edge_p(wh10, w21.y, (w0 >> 5) & 1);
            float e6 = edge_p(wh10, w21.z, (w0 >> 6) & 1);
            float e7 = edge_p(wh10, w21.w, (w0 >> 7) & 1);
            ps0 += ((e0 + e1) + (e2 + e3)) + ((e4 + e5) + (e6 + e7));
            u32x4 uv0;
            uv0.x = packbf2(e0, e1); uv0.y = packbf2(e2, e3);
            uv0.z = packbf2(e4, e5); uv0.w = packbf2(e6, e7);

            float f0 = edge_p(wh11, w20.x, (w1 >> 0) & 1);
            float f1 = edge_p(wh11, w20.y, (w1 >> 1) & 1);
            float f2 = edge_p(wh11, w20.z, (w1 >> 2) & 1);
            float f3 = edge_p(wh11, w20.w, (w1 >> 3) & 1);
            float f4 = edge_p(wh11, w21.x, (w1 >> 4) & 1);
            float f5 = edge_p(wh11, w21.y, (w1 >> 5) & 1);
            float f6 = edge_p(wh11, w21.z, (w1 >> 6) & 1);
            float f7 = edge_p(wh11, w21.w, (w1 >> 7) & 1);
            ps1 += ((f0 + f1) + (f2 + f3)) + ((f4 + f5) + (f6 + f7));
            u32x4 uv1;
            uv1.x = packbf2(f0, f1); uv1.y = packbf2(f2, f3);
            uv1.z = packbf2(f4, f5); uv1.w = packbf2(f6, f7);

            s16x8 af0 = __builtin_bit_cast(s16x8, uv0);
            s16x8 af1 = __builtin_bit_cast(s16x8, uv1);

            #pragma unroll
            for (int nt = 0; nt < 8; nt++) {
                s16x8 b = Hf[(kt * 8 + nt) * 64 + lane];
                acc0[nt] = __builtin_amdgcn_mfma_f32_16x16x32_bf16(af0, b, acc0[nt], 0, 0, 0);
                acc1[nt] = __builtin_amdgcn_mfma_f32_16x16x32_bf16(af1, b, acc1[nt], 0, 0, 0);
            }
        }
    }

    // rowsums: reduce across quads; lanes 0..15 hold rows (lo half / hi half)
    ps0 += __shfl_xor(ps0, 16, 64); ps0 += __shfl_xor(ps0, 32, 64);
    ps1 += __shfl_xor(ps1, 16, 64); ps1 += __shfl_xor(ps1, 32, 64);
    if (lane < 16) {
        rsum_lds[wave][lane] = ps0;
        rsum_lds[wave][lane + 16] = ps1;
    }

    // park accumulators: idx 0..7 = acc0[nt] (rows 0-15), 8..15 = acc1[nt]
    #pragma unroll
    for (int nt = 0; nt < 8; nt++) {
        red[wave][nt][lane] = acc0[nt];
        red[wave][nt + 8][lane] = acc1[nt];
    }
    __syncthreads();

    // finalize: wave w reduces slices i = w (rows 0-15, nt=w) and
    // i = w+8 (rows 16-31, nt=w) across the 8 stripes, divides, writes out.
    #pragma unroll
    for (int half = 0; half < 2; half++) {
        int i = wave + half * 8;
        int rowoff = half * 16;
        f32x4 s = red[0][i][lane];
        #pragma unroll
        for (int p2 = 1; p2 < NSTRIPE; p2++) s += red[p2][i][lane];

        #pragma unroll
        for (int reg = 0; reg < 4; reg++) {
            int rowl = quad * 4 + reg;
            float sum = 0.f;
            #pragma unroll
            for (int p2 = 0; p2 < NSTRIPE; p2++) sum += rsum_lds[p2][rowoff + rowl];
            float r = __builtin_amdgcn_rcpf(sum);
            r = r * (2.0f - sum * r);   // Newton refine
            out[(size_t)(rbase + rowoff + rowl) * OUT_F + wave * 16 + lid] = s[reg] * r;
        }
    }
}

extern "C" void kernel_launch(void* const* d_in, const int* in_sizes, int n_in,
                              void* d_out, int out_size, void* d_ws, size_t ws_size,
                              hipStream_t stream) {
    const float* X   = (const float*)d_in[0];
    const int*   adj = (const int*)d_in[1];
    const float* W   = (const float*)d_in[2];
    const float* a1  = (const float*)d_in[3];
    const float* a2  = (const float*)d_in[4];

    char* ws = (char*)d_ws;
    float* Wh1 = (float*)(ws);                         // 32 KB
    float* Wh2 = (float*)(ws + (32 << 10));            // 32 KB
    float* Wa1 = (float*)(ws + (64 << 10));            // 2 KB
    float* Wa2 = (float*)(ws + (66 << 10));            // 2 KB
    u16* W_frag = (u16*)(ws + (128 << 10));            // 128 KB
    u16* h_frag = (u16*)(ws + (256 << 10));            // 2 MB (ends 2.25 MB)
    u32* Pk     = (u32*)(ws + ((size_t)4 << 20));      // 8 MB packed adj
    float* out = (float*)d_out;

    hipLaunchKernelGGL(repack_W, dim3(256), dim3(256), 0, stream, W, W_frag);
    hipLaunchKernelGGL(compute_Wa, dim3(2), dim3(256), 0, stream, W, a1, a2, Wa1, Wa2);
    hipLaunchKernelGGL(pack_adj, dim3(N_NODES * NWORDS / 256), dim3(256), 0, stream, adj, Pk);
    hipLaunchKernelGGL(gemm_h, dim3(512), dim3(256), 0, stream,
                       X, W_frag, Wa1, Wa2, Wh1, Wh2, h_frag);
    hipLaunchKernelGGL(attn_fused, dim3(N_NODES / 32), dim3(512), 0, stream,
                       Pk, Wh1, Wh2, h_frag, out);
}

// Round 5
// 452.266 us; speedup vs baseline: 1.0374x; 1.0374x over previous
//
#include <hip/hip_runtime.h>
#include <hip/hip_bf16.h>

#define N_NODES 8192
#define IN_F 512
#define OUT_F 128
#define NSTRIPE 8                 // k-stripes per block = waves per block
#define KT_PER 32                 // 32-col k-tiles per stripe
#define NWORDS (N_NODES / 32)     // packed words per adj row = 256
#define LOG2E 1.4426950408889634f

typedef unsigned short u16;
typedef unsigned int u32;
typedef short s16x8 __attribute__((ext_vector_type(8)));
typedef float f32x4 __attribute__((ext_vector_type(4)));
typedef u32 u32x4 __attribute__((ext_vector_type(4)));

__device__ __forceinline__ u16 f2bf(float f) {
    union { float f; unsigned u; } x; x.f = f;
    unsigned r = x.u + 0x7FFFu + ((x.u >> 16) & 1u);
    return (u16)(r >> 16);
}

// HW pack: v_cvt_pk_bf16_f32 (rne) -> u32 (lo=a, hi=b)
__device__ __forceinline__ u32 packbf2(float a, float b) {
    __hip_bfloat162 h = __float22bfloat162_rn(make_float2(a, b));
    u32 u; __builtin_memcpy(&u, &h, 4);
    return u;
}

// edge weight: exp(sigmoid(alpha)) or 0 if masked
__device__ __forceinline__ float edge_p(float wh1, float w2, int keep) {
    float alpha = wh1 + w2;
    float e = exp2f(-LOG2E * alpha);
    float s = __builtin_amdgcn_rcpf(1.0f + e);
    float p = exp2f(LOG2E * s);
    return keep ? p : 0.0f;
}

// ---- K0: repack W [512x128] fp32 -> bf16 MFMA B-fragment layout
__global__ void repack_W(const float* __restrict__ W, u16* __restrict__ W_frag) {
    int tid = blockIdx.x * 256 + threadIdx.x;   // 0..65535
    int j = tid & 7;
    int lane = (tid >> 3) & 63;
    int nt = (tid >> 9) & 7;
    int kt = tid >> 12;
    int k = kt * 32 + (lane >> 4) * 8 + j;
    int n = nt * 16 + (lane & 15);
    W_frag[tid] = f2bf(W[k * OUT_F + n]);
}

// ---- Wa1 = W@a1, Wa2 = W@a2 (fp32, 512 each)
__global__ void compute_Wa(const float* __restrict__ W, const float* __restrict__ a1,
                           const float* __restrict__ a2,
                           float* __restrict__ Wa1, float* __restrict__ Wa2) {
    int k = blockIdx.x * 256 + threadIdx.x;
    if (k >= IN_F) return;
    float s1 = 0.f, s2 = 0.f;
    #pragma unroll 8
    for (int n = 0; n < OUT_F; n++) {
        float w = W[k * OUT_F + n];
        s1 += w * a1[n];
        s2 += w * a2[n];
    }
    Wa1[k] = s1; Wa2[k] = s2;
}

// ---- K-pack: adj int32 [8192x8192] -> 1-bit bitmap, 256 MB -> 8 MB.
__global__ __launch_bounds__(256)
void pack_adj(const int* __restrict__ adj, u32* __restrict__ Pk) {
    int gid = blockIdx.x * 256 + threadIdx.x;       // word index, 2M total
    const int* src = adj + (size_t)gid * 32;
    u32 b = 0;
    #pragma unroll
    for (int t = 0; t < 8; t++) {
        int4 v = *(const int4*)(src + t * 4);
        b |= (u32)(v.x > 0) << (t * 4 + 0);
        b |= (u32)(v.y > 0) << (t * 4 + 1);
        b |= (u32)(v.z > 0) << (t * 4 + 2);
        b |= (u32)(v.w > 0) << (t * 4 + 3);
    }
    Pk[gid] = b;
}

// ---- K1: h = X@W (bf16 MFMA), scatter h to B-frag layout; Wh = X@Wa (fp32).
// R5: vmcnt-pure loop — ALL global loads (X, Wf, Wa) are one-kt-ahead
// register prefetches, so the MFMA's s_waitcnt never drains the pipeline.
__global__ __launch_bounds__(256)
void gemm_h(const float* __restrict__ X, const u16* __restrict__ W_frag,
            const float* __restrict__ Wa1, const float* __restrict__ Wa2,
            float* __restrict__ Wh1, float* __restrict__ Wh2,
            u16* __restrict__ h_frag) {
    int tid = threadIdx.x;
    int wave = tid >> 6;
    int lane = tid & 63;
    int quad = lane >> 4;
    int lid = lane & 15;
    int rbase = blockIdx.x * 16;
    const float* xrow = X + (size_t)(rbase + lid) * IN_F;
    const s16x8* Wf = (const s16x8*)W_frag;
    f32x4 acc0 = {}, acc1 = {};
    float p1 = 0.f, p2 = 0.f;
    int nt0 = wave * 2;

    // prologue prefetch: kt = 0
    int k0p = quad * 8;
    float4 X0 = *(const float4*)(xrow + k0p);
    float4 X1 = *(const float4*)(xrow + k0p + 4);
    s16x8 B0 = Wf[nt0 * 64 + lane];
    s16x8 B1 = Wf[(nt0 + 1) * 64 + lane];
    float4 A0 = {}, A1 = {}, C0 = {}, C1 = {};
    if (wave == 0) {
        A0 = *(const float4*)(Wa1 + k0p); A1 = *(const float4*)(Wa1 + k0p + 4);
        C0 = *(const float4*)(Wa2 + k0p); C1 = *(const float4*)(Wa2 + k0p + 4);
    }

    #pragma unroll 1
    for (int kt = 0; kt < 16; kt++) {
        // consume copies
        float4 x0 = X0, x1 = X1;
        s16x8 b0 = B0, b1 = B1;
        float4 wa = A0, wb = A1, wc = C0, wd = C1;
        // issue next-kt loads immediately (clamped — no OOB, no drain)
        int ktn = (kt + 1 < 16) ? kt + 1 : kt;
        int k0n = ktn * 32 + quad * 8;
        X0 = *(const float4*)(xrow + k0n);
        X1 = *(const float4*)(xrow + k0n + 4);
        B0 = Wf[(ktn * 8 + nt0) * 64 + lane];
        B1 = Wf[(ktn * 8 + nt0 + 1) * 64 + lane];
        if (wave == 0) {
            A0 = *(const float4*)(Wa1 + k0n); A1 = *(const float4*)(Wa1 + k0n + 4);
            C0 = *(const float4*)(Wa2 + k0n); C1 = *(const float4*)(Wa2 + k0n + 4);
        }

        u32x4 uv;
        uv.x = packbf2(x0.x, x0.y); uv.y = packbf2(x0.z, x0.w);
        uv.z = packbf2(x1.x, x1.y); uv.w = packbf2(x1.z, x1.w);
        s16x8 a = __builtin_bit_cast(s16x8, uv);
        if (wave == 0) {
            p1 += x0.x*wa.x + x0.y*wa.y + x0.z*wa.z + x0.w*wa.w
                + x1.x*wb.x + x1.y*wb.y + x1.z*wb.z + x1.w*wb.w;
            p2 += x0.x*wc.x + x0.y*wc.y + x0.z*wc.z + x0.w*wc.w
                + x1.x*wd.x + x1.y*wd.y + x1.z*wd.z + x1.w*wd.w;
        }
        acc0 = __builtin_amdgcn_mfma_f32_16x16x32_bf16(a, b0, acc0, 0, 0, 0);
        acc1 = __builtin_amdgcn_mfma_f32_16x16x32_bf16(a, b1, acc1, 0, 0, 0);
    }

    #pragma unroll
    for (int reg = 0; reg < 4; reg++) {
        int row = rbase + quad * 4 + reg;
        int ktile = row >> 5, kl = row & 31;
        int lane2 = (kl >> 3) * 16 + lid, j2 = kl & 7;
        h_frag[(size_t)((ktile * 8 + nt0) * 64 + lane2) * 8 + j2] = f2bf(acc0[reg]);
        h_frag[(size_t)((ktile * 8 + nt0 + 1) * 64 + lane2) * 8 + j2] = f2bf(acc1[reg]);
    }
    if (wave == 0) {
        p1 += __shfl_xor(p1, 16, 64); p1 += __shfl_xor(p1, 32, 64);
        p2 += __shfl_xor(p2, 16, 64); p2 += __shfl_xor(p2, 32, 64);
        if (lane < 16) { Wh1[rbase + lid] = p1; Wh2[rbase + lid] = p2; }
    }
}

// ---- K2: fused attention on packed adjacency — vmcnt-PURE inner loop.
// 256 blocks x 512 thr; wave p sweeps k-stripe [p*1024, +1024) over 32 rows.
// All VMEM is forward prefetch: Hf fragments double-buffered (hb0/hb1,
// statically indexed) one kt ahead; Pk words one 4-kt group ahead (consumed
// via static .x/.y/.z/.w). Wh2 lives in LDS (lgkmcnt — separate counter, so
// its waits can't drain the vmem pipeline). LDS: Wh2 32 KB aliases the first
// quarter of the 128 KB park buffer (dead until after the sweep).
__global__ __launch_bounds__(512)
void attn_fused(const u32* __restrict__ Pk, const float* __restrict__ Wh1,
                const float* __restrict__ Wh2, const u16* __restrict__ h_frag,
                float* __restrict__ out) {
    __shared__ f32x4 red[NSTRIPE][16][64];   // 128 KB acc park (sweep: first 32 KB = Wh2_lds)
    __shared__ float rsum_lds[NSTRIPE][32];  // 1 KB rowsums
    float* Wh2_lds = (float*)&red[0][0][0];

    int tid = threadIdx.x;
    int wave = tid >> 6;         // = stripe p
    int lane = tid & 63;
    int quad = lane >> 4;
    int lid = lane & 15;
    int rbase = blockIdx.x * 32;
    int r0 = rbase + lid, r1 = r0 + 16;

    // stage Wh2 (8192 f32 = 32 KB) into LDS: 512 thr x 4 float4
    {
        const float4* s = (const float4*)Wh2;
        float4* d = (float4*)Wh2_lds;
        #pragma unroll
        for (int i = 0; i < 4; i++) d[tid + i * 512] = s[tid + i * 512];
    }
    float wh10 = Wh1[r0], wh11 = Wh1[r1];
    __syncthreads();

    f32x4 acc0[8] = {}, acc1[8] = {};
    float ps0 = 0.f, ps1 = 0.f;
    const s16x8* Hf = (const s16x8*)h_frag;
    const u32* prow0 = Pk + (size_t)r0 * NWORDS;
    const u32* prow1 = Pk + (size_t)r1 * NWORDS;
    const int kt0 = wave * KT_PER;

    // prologue: group 0's Pk words + kt0's Hf fragments
    u32x4 PA = *(const u32x4*)(prow0 + kt0);
    u32x4 PB = *(const u32x4*)(prow1 + kt0);
    s16x8 hb0[8], hb1[8];
    #pragma unroll
    for (int nt = 0; nt < 8; nt++) hb0[nt] = Hf[(kt0 * 8 + nt) * 64 + lane];

    // one kt: consume cur[], prefetch nxt[] (issue-first), edges from pw bits
    auto step = [&](int i, u32 pw0, u32 pw1, s16x8 (&cur)[8], s16x8 (&nxt)[8]) {
        int kt = kt0 + i;
        int ktn = (i + 1 < KT_PER) ? kt + 1 : kt;   // clamp
        #pragma unroll
        for (int nt = 0; nt < 8; nt++) nxt[nt] = Hf[(ktn * 8 + nt) * 64 + lane];

        int k0 = kt * 32 + quad * 8;
        float4 w20 = *(const float4*)(Wh2_lds + k0);     // ds_read_b128
        float4 w21 = *(const float4*)(Wh2_lds + k0 + 4);
        u32 w0 = pw0 >> (quad * 8);
        u32 w1 = pw1 >> (quad * 8);

        float e0 = edge_p(wh10, w20.x, (w0 >> 0) & 1);
        float e1 = edge_p(wh10, w20.y, (w0 >> 1) & 1);
        float e2 = edge_p(wh10, w20.z, (w0 >> 2) & 1);
        float e3 = edge_p(wh10, w20.w, (w0 >> 3) & 1);
        float e4 = edge_p(wh10, w21.x, (w0 >> 4) & 1);
        float e5 = edge_p(wh10, w21.y, (w0 >> 5) & 1);
        float e6 = edge_p(wh10, w21.z, (w0 >> 6) & 1);
        float e7 = edge_p(wh10, w21.w, (w0 >> 7) & 1);
        ps0 += ((e0 + e1) + (e2 + e3)) + ((e4 + e5) + (e6 + e7));
        u32x4 uv0;
        uv0.x = packbf2(e0, e1); uv0.y = packbf2(e2, e3);
        uv0.z = packbf2(e4, e5); uv0.w = packbf2(e6, e7);

        float f0 = edge_p(wh11, w20.x, (w1 >> 0) & 1);
        float f1 = edge_p(wh11, w20.y, (w1 >> 1) & 1);
        float f2 = edge_p(wh11, w20.z, (w1 >> 2) & 1);
        float f3 = edge_p(wh11, w20.w, (w1 >> 3) & 1);
        float f4 = edge_p(wh11, w21.x, (w1 >> 4) & 1);
        float f5 = edge_p(wh11, w21.y, (w1 >> 5) & 1);
        float f6 = edge_p(wh11, w21.z, (w1 >> 6) & 1);
        float f7 = edge_p(wh11, w21.w, (w1 >> 7) & 1);
        ps1 += ((f0 + f1) + (f2 + f3)) + ((f4 + f5) + (f6 + f7));
        u32x4 uv1;
        uv1.x = packbf2(f0, f1); uv1.y = packbf2(f2, f3);
        uv1.z = packbf2(f4, f5); uv1.w = packbf2(f6, f7);

        s16x8 af0 = __builtin_bit_cast(s16x8, uv0);
        s16x8 af1 = __builtin_bit_cast(s16x8, uv1);

        #pragma unroll
        for (int nt = 0; nt < 8; nt++) {
            acc0[nt] = __builtin_amdgcn_mfma_f32_16x16x32_bf16(af0, cur[nt], acc0[nt], 0, 0, 0);
            acc1[nt] = __builtin_amdgcn_mfma_f32_16x16x32_bf16(af1, cur[nt], acc1[nt], 0, 0, 0);
        }
    };

    #pragma unroll 1
    for (int g = 0; g < KT_PER / 4; g++) {
        int base = g * 4;
        u32x4 cPA = PA, cPB = PB;   // consume copies (static element access)
        int gb = (g + 1 < KT_PER / 4) ? (kt0 + base + 4) : kt0;  // clamp
        PA = *(const u32x4*)(prow0 + gb);
        PB = *(const u32x4*)(prow1 + gb);
        step(base + 0, cPA.x, cPB.x, hb0, hb1);
        step(base + 1, cPA.y, cPB.y, hb1, hb0);
        step(base + 2, cPA.z, cPB.z, hb0, hb1);
        step(base + 3, cPA.w, cPB.w, hb1, hb0);
    }

    // rowsums: reduce across quads; lanes 0..15 hold rows (lo/hi half)
    ps0 += __shfl_xor(ps0, 16, 64); ps0 += __shfl_xor(ps0, 32, 64);
    ps1 += __shfl_xor(ps1, 16, 64); ps1 += __shfl_xor(ps1, 32, 64);
    if (lane < 16) {
        rsum_lds[wave][lane] = ps0;
        rsum_lds[wave][lane + 16] = ps1;
    }

    // all Wh2_lds readers must be done before the park clobbers the alias
    __syncthreads();

    #pragma unroll
    for (int nt = 0; nt < 8; nt++) {
        red[wave][nt][lane] = acc0[nt];
        red[wave][nt + 8][lane] = acc1[nt];
    }
    __syncthreads();

    // finalize: wave w reduces slices i = w (rows 0-15) and i = w+8
    // (rows 16-31) across the 8 stripes, divides, writes final out.
    #pragma unroll
    for (int half = 0; half < 2; half++) {
        int i = wave + half * 8;
        int rowoff = half * 16;
        f32x4 s = red[0][i][lane];
        #pragma unroll
        for (int p2 = 1; p2 < NSTRIPE; p2++) s += red[p2][i][lane];

        #pragma unroll
        for (int reg = 0; reg < 4; reg++) {
            int rowl = quad * 4 + reg;
            float sum = 0.f;
            #pragma unroll
            for (int p2 = 0; p2 < NSTRIPE; p2++) sum += rsum_lds[p2][rowoff + rowl];
            float r = __builtin_amdgcn_rcpf(sum);
            r = r * (2.0f - sum * r);   // Newton refine
            out[(size_t)(rbase + rowoff + rowl) * OUT_F + wave * 16 + lid] = s[reg] * r;
        }
    }
}

extern "C" void kernel_launch(void* const* d_in, const int* in_sizes, int n_in,
                              void* d_out, int out_size, void* d_ws, size_t ws_size,
                              hipStream_t stream) {
    const float* X   = (const float*)d_in[0];
    const int*   adj = (const int*)d_in[1];
    const float* W   = (const float*)d_in[2];
    const float* a1  = (const float*)d_in[3];
    const float* a2  = (const float*)d_in[4];

    char* ws = (char*)d_ws;
    float* Wh1 = (float*)(ws);                         // 32 KB
    float* Wh2 = (float*)(ws + (32 << 10));            // 32 KB
    float* Wa1 = (float*)(ws + (64 << 10));            // 2 KB
    float* Wa2 = (float*)(ws + (66 << 10));            // 2 KB
    u16* W_frag = (u16*)(ws + (128 << 10));            // 128 KB
    u16* h_frag = (u16*)(ws + (256 << 10));            // 2 MB (ends 2.25 MB)
    u32* Pk     = (u32*)(ws + ((size_t)4 << 20));      // 8 MB packed adj
    float* out = (float*)d_out;

    hipLaunchKernelGGL(repack_W, dim3(256), dim3(256), 0, stream, W, W_frag);
    hipLaunchKernelGGL(compute_Wa, dim3(2), dim3(256), 0, stream, W, a1, a2, Wa1, Wa2);
    hipLaunchKernelGGL(pack_adj, dim3(N_NODES * NWORDS / 256), dim3(256), 0, stream, adj, Pk);
    hipLaunchKernelGGL(gemm_h, dim3(512), dim3(256), 0, stream,
                       X, W_frag, Wa1, Wa2, Wh1, Wh2, h_frag);
    hipLaunchKernelGGL(attn_fused, dim3(N_NODES / 32), dim3(512), 0, stream,
                       Pk, Wh1, Wh2, h_frag, out);
}